// Round 5
// baseline (201.545 us; speedup 1.0000x reference)
//
#include <hip/hip_runtime.h>
#include <hip/hip_fp16.h>

#define NCH    40
#define MORD   16
#define NR     17
#define NBINS  257
#define FPB    64                // frames per block = threads per block (ONE wave)

// ---------------- compile-time table generation (double precision) ----------------
namespace cfg {

constexpr double PI  = 3.14159265358979323846264338327950288;
constexpr double LN2 = 0.693147180559945309417232121458176568;

constexpr double cexp(double x) {
    double t = 1.0, s = 1.0;
    for (int i = 1; i < 40; ++i) { t *= x / i; s += t; }
    return s;
}

constexpr double clog(double z) {
    double lg = 0.0;
    while (z > 1.4142135623730951) { z *= 0.5; lg += LN2; }
    while (z < 0.7071067811865476) { z *= 2.0; lg -= LN2; }
    double u = (z - 1.0) / (z + 1.0), u2 = u * u, t = u, s = u;
    for (int k = 1; k < 24; ++k) { t *= u2; s += t / (2.0 * k + 1.0); }
    return lg + 2.0 * s;
}

constexpr double ccos(double x) {
    double tp = 2.0 * PI;
    double q = x / tp;
    long long k = (long long)(q + (q >= 0.0 ? 0.5 : -0.5));
    double r = x - (double)k * tp;
    double r2 = r * r, t = 1.0, s = 1.0;
    for (int i = 1; i < 20; ++i) { t *= -r2 / ((2.0 * i - 1.0) * (2.0 * i)); s += t; }
    return s;
}

constexpr double csin(double x) { return ccos(x - PI / 2.0); }

struct Tab {
    int   start[43];     // start[c] = first bin with t_b > c
    int   chan[257];     // segment id c(b), 0..40 (bins 0 and 256 have w=0,c=0 -> pruned)
    float w[257];        // t_b - c(b), in [0,1)
    float eql[NCH];
    float lift[NR];
    float ctf[NR][21];   // folded cosine: r[l] = sum_j ctf[l][j]*(ys[j] +- ys[41-j])
    constexpr Tab() : start(), chan(), w(), eql(), lift(), ctf() {
        const double lmax  = clog(87.0 / 7.0);
        const double U1127 = lmax / 41.0;
        for (int c = 0; c <= 41; ++c) {
            double thr = 22.4 * (cexp((double)c * U1127) - 1.0);
            int s = (int)thr + 1;
            if (s < 1) s = 1;
            if (s > 256) s = 256;
            start[c] = s;
        }
        start[42] = start[41];
        for (int c = 0; c <= 40; ++c) {
            for (int b = start[c]; b < start[c + 1]; ++b) {
                double mel = 1127.0 * clog(1.0 + (double)b * 31.25 / 700.0);
                double t   = mel / (1127.0 * U1127);
                w[b] = (float)(t - (double)c);
                chan[b] = c;
            }
        }
        for (int c = 0; c < NCH; ++c) {
            double cf = 700.0 * (cexp((double)(c + 1) * U1127) - 1.0);
            double f2 = cf * cf;
            double e  = f2 / (f2 + 160000.0);
            e = e * e * (f2 + 1440000.0) / (f2 + 9610000.0);
            eql[c] = (float)e;
        }
        for (int m = 0; m < NR; ++m)
            lift[m] = (float)(1.0 + 11.0 * csin(PI * (double)m / 22.0));
        lift[0] = 2.0f;
        for (int l = 0; l < NR; ++l)
            for (int j = 0; j <= 20; ++j) {
                double s = (j == 0) ? 1.0 : 2.0;
                ctf[l][j] = (float)(s * ccos(PI * (double)(j * l) / 41.0) / 82.0);
            }
    }
};

constexpr Tab T{};

} // namespace cfg

// One wave per block, 64 frames, 4 independent blocks/CU (LDS 32896 B), NO s_barrier:
//  - stage: block's 64 frames are one contiguous 16B-aligned 65792 B range; 64 rounds
//    of global dwordx4 -> 2x cvt_pk -> ds_write_b64 at byte 8i (identity layout).
//  - wave-local s_waitcnt replaces __syncthreads (block == wave; LDS is private).
//  - compute: scalar ds_read_u16 per bin (base l*257 halves; 2 lanes/bank = free),
//    literal weights/channels; compute hides under the other 3 blocks' staging.
__global__ __launch_bounds__(FPB) void plp_kernel(const float* __restrict__ x,
                                                  float* __restrict__ out,
                                                  int nframes)
{
    using cfg::T;
    __shared__ __half slabH[FPB * NBINS];        // 32896 B -> 4 blocks/CU

    const int tid = threadIdx.x;                 // 0..63
    const long long F0 = (long long)blockIdx.x * FPB;

    // ---- linear coalesced staging: 4112 float4s = 64 frames x 257 floats ----
    {
        const float4* src = reinterpret_cast<const float4*>(x + F0 * NBINS);
        uint2* dst = reinterpret_cast<uint2*>(slabH);
        #pragma unroll 16
        for (int r = 0; r < 64; ++r) {
            const int i = (r << 6) + tid;        // float4 index within slab
            const float4 v = src[i];
            union { __half2 h[2]; uint2 u; } cv;
            cv.h[0] = __float22half2_rn(make_float2(v.x, v.y));
            cv.h[1] = __float22half2_rn(make_float2(v.z, v.w));
            dst[i] = cv.u;                       // byte 8i, aligned b64
        }
        if (tid < 16) {                          // tail: 4112 - 64*64 = 16
            const int i = 4096 + tid;
            const float4 v = src[i];
            union { __half2 h[2]; uint2 u; } cv;
            cv.h[0] = __float22half2_rn(make_float2(v.x, v.y));
            cv.h[1] = __float22half2_rn(make_float2(v.z, v.w));
            dst[i] = cv.u;
        }
    }
    // block == one wave: wave-local drain orders ds_write -> ds_read; no s_barrier
    asm volatile("s_waitcnt vmcnt(0) lgkmcnt(0)" ::: "memory");

    const long long frame = F0 + tid;
    const __half* fr = &slabH[tid * NBINS];

    // ---- sparse mel filterbank: scalar u16 reads, literal weights ----
    float fb[NCH];
    #pragma unroll
    for (int c = 0; c < NCH; ++c) fb[c] = 0.f;

    #pragma unroll
    for (int b = 1; b <= 255; ++b) {             // bins 0 and 256 carry zero weight
        const float xv = __half2float(fr[b]);
        const int   ch = T.chan[b];
        const float wa = T.w[b];
        if (ch < NCH) fb[ch]     = fmaf(wa, xv, fb[ch]);
        if (ch >= 1)  fb[ch - 1] = fmaf(1.0f - wa, xv, fb[ch - 1]);
    }

    // ---- equal-loudness + cube-root compression (fast log/exp), ys in regs ----
    float yv[NCH];
    #pragma unroll
    for (int c = 0; c < NCH; ++c) {
        float v = fmaxf(fb[c], 1e-5f) * T.eql[c];
        yv[c] = __expf(0.33f * __logf(v));
    }

    // ---- even/odd fold of y (42 taps incl. duplicated edges) ----
    float ye[21], yo[21];
    ye[0] = yv[0] + yv[39];  yo[0] = yv[0] - yv[39];       // ys[0], ys[41]
    #pragma unroll
    for (int jj = 1; jj <= 20; ++jj) {
        float aa = yv[jj - 1], bb = yv[40 - jj];           // ys[j], ys[41-j]
        ye[jj] = aa + bb;  yo[jj] = aa - bb;
    }

    // ---- folded cosine transform: 17 lags x 21 taps, literal coefficients ----
    float rr[NR];
    #pragma unroll
    for (int lg = 0; lg < NR; ++lg) {
        const float* yy = (lg & 1) ? yo : ye;
        float acc = 0.f;
        #pragma unroll
        for (int jj = 0; jj <= 20; ++jj) acc = fmaf(T.ctf[lg][jj], yy[jj], acc);
        rr[lg] = acc;
    }

    // ---- Levinson-Durbin (unrolled, v_rcp) ----
    float a[MORD];
    #pragma unroll
    for (int i = 0; i < MORD; ++i) a[i] = 0.f;
    float E = rr[0];
    #pragma unroll
    for (int i = 1; i <= MORD; ++i) {
        float acc = rr[i];
        #pragma unroll
        for (int jj = 0; jj < i - 1; ++jj) acc = fmaf(a[jj], rr[i - 1 - jj], acc);
        float k = -acc * __builtin_amdgcn_rcpf(E);
        const int half = (i - 1) / 2;
        #pragma unroll
        for (int jj = 0; jj < half; ++jj) {
            float t1 = a[jj], t2 = a[i - 2 - jj];
            a[jj]         = fmaf(k, t2, t1);
            a[i - 2 - jj] = fmaf(k, t1, t2);
        }
        if ((i - 1) & 1) a[half] = fmaf(k, a[half], a[half]);
        a[i - 1] = k;
        E = E * (1.f - k * k);
    }

    // ---- cepstrum (c[0] unused; ccs[k]=k*cc[k] keeps inner fma literal-free) ----
    float cc[NR], ccs[NR];
    #pragma unroll
    for (int m = 1; m <= MORD; ++m) {
        float acc = 0.f;
        #pragma unroll
        for (int k2 = 1; k2 < m; ++k2)
            acc = fmaf(ccs[k2], a[m - k2 - 1], acc);
        float cm = -(a[m - 1] + acc * (1.0f / (float)m));
        cc[m]  = cm;
        ccs[m] = (float)m * cm;
    }

    // ---- direct stores: thread's 4x float4 cover its frame's full 64B line ----
    if (frame < (long long)nframes) {
        float o[16];
        #pragma unroll
        for (int m = 1; m <= MORD; ++m) o[m - 1] = cc[m] * T.lift[m];

        float4* op = reinterpret_cast<float4*>(out + (size_t)frame * 16);
        op[0] = make_float4(o[0],  o[1],  o[2],  o[3]);
        op[1] = make_float4(o[4],  o[5],  o[6],  o[7]);
        op[2] = make_float4(o[8],  o[9],  o[10], o[11]);
        op[3] = make_float4(o[12], o[13], o[14], o[15]);
    }
}

extern "C" void kernel_launch(void* const* d_in, const int* in_sizes, int n_in,
                              void* d_out, int out_size, void* d_ws, size_t ws_size,
                              hipStream_t stream) {
    const float* x   = (const float*)d_in[0];
    float*      outp = (float*)d_out;
    int nframes = in_sizes[0] / NBINS;                 // 131072 (multiple of FPB)
    int nblocks = (nframes + FPB - 1) / FPB;           // 2048 blocks, 4 resident/CU
    plp_kernel<<<nblocks, FPB, 0, stream>>>(x, outp, nframes);
}

// Round 6
// 200.641 us; speedup vs baseline: 1.0045x; 1.0045x over previous
//
#include <hip/hip_runtime.h>
#include <hip/hip_fp16.h>

#define NCH    40
#define MORD   16
#define NR     17
#define NBINS  257
#define TPB    256               // 4 waves: 0-1 stage, 2-3 compute
#define CFRM   128               // frames per generation (one slab)
#define GENS   4                 // generations per block (512 frames/block)

// ---------------- compile-time table generation (double precision) ----------------
namespace cfg {

constexpr double PI  = 3.14159265358979323846264338327950288;
constexpr double LN2 = 0.693147180559945309417232121458176568;

constexpr double cexp(double x) {
    double t = 1.0, s = 1.0;
    for (int i = 1; i < 40; ++i) { t *= x / i; s += t; }
    return s;
}

constexpr double clog(double z) {
    double lg = 0.0;
    while (z > 1.4142135623730951) { z *= 0.5; lg += LN2; }
    while (z < 0.7071067811865476) { z *= 2.0; lg -= LN2; }
    double u = (z - 1.0) / (z + 1.0), u2 = u * u, t = u, s = u;
    for (int k = 1; k < 24; ++k) { t *= u2; s += t / (2.0 * k + 1.0); }
    return lg + 2.0 * s;
}

constexpr double ccos(double x) {
    double tp = 2.0 * PI;
    double q = x / tp;
    long long k = (long long)(q + (q >= 0.0 ? 0.5 : -0.5));
    double r = x - (double)k * tp;
    double r2 = r * r, t = 1.0, s = 1.0;
    for (int i = 1; i < 20; ++i) { t *= -r2 / ((2.0 * i - 1.0) * (2.0 * i)); s += t; }
    return s;
}

constexpr double csin(double x) { return ccos(x - PI / 2.0); }

struct Tab {
    int   start[43];     // start[c] = first bin with t_b > c
    int   chan[257];     // segment id c(b), 0..40 (bins 0 and 256 carry zero weight)
    float w[257];        // t_b - c(b), in [0,1)
    float eql[NCH];
    float lift[NR];
    float ctf[NR][21];   // folded cosine: r[l] = sum_j ctf[l][j]*(ys[j] +- ys[41-j])
    constexpr Tab() : start(), chan(), w(), eql(), lift(), ctf() {
        const double lmax  = clog(87.0 / 7.0);
        const double U1127 = lmax / 41.0;
        for (int c = 0; c <= 41; ++c) {
            double thr = 22.4 * (cexp((double)c * U1127) - 1.0);
            int s = (int)thr + 1;
            if (s < 1) s = 1;
            if (s > 256) s = 256;
            start[c] = s;
        }
        start[42] = start[41];
        for (int c = 0; c <= 40; ++c) {
            for (int b = start[c]; b < start[c + 1]; ++b) {
                double mel = 1127.0 * clog(1.0 + (double)b * 31.25 / 700.0);
                double t   = mel / (1127.0 * U1127);
                w[b] = (float)(t - (double)c);
                chan[b] = c;
            }
        }
        for (int c = 0; c < NCH; ++c) {
            double cf = 700.0 * (cexp((double)(c + 1) * U1127) - 1.0);
            double f2 = cf * cf;
            double e  = f2 / (f2 + 160000.0);
            e = e * e * (f2 + 1440000.0) / (f2 + 9610000.0);
            eql[c] = (float)e;
        }
        for (int m = 0; m < NR; ++m)
            lift[m] = (float)(1.0 + 11.0 * csin(PI * (double)m / 22.0));
        lift[0] = 2.0f;
        for (int l = 0; l < NR; ++l)
            for (int j = 0; j <= 20; ++j) {
                double s = (j == 0) ? 1.0 : 2.0;
                ctf[l][j] = (float)(s * ccos(PI * (double)(j * l) / 41.0) / 82.0);
            }
    }
};

constexpr Tab T{};

} // namespace cfg

// ---- filterbank over 128 half2 pairs; PAR=0: bins (2p,2p+1), PAR=1: bins (2p+1,2p+2).
// ---- All weights/channels are compile-time literals; zero-weight edge bins pruned.
template<int PAR>
__device__ __forceinline__ void fbank_pairs(const __half2* __restrict__ fr2, float fb[NCH])
{
    using cfg::T;
    #pragma unroll
    for (int p = 0; p < 128; ++p) {
        const float2 xp = __half22float2(fr2[p]);
        {
            const int   bb = 2 * p + PAR;
            const int   ch = T.chan[bb];
            const float wa = T.w[bb];
            if (wa != 0.f || ch != 0) {                 // constant-folded per p
                if (ch < NCH) fb[ch]     = fmaf(wa, xp.x, fb[ch]);
                if (ch >= 1)  fb[ch - 1] = fmaf(1.0f - wa, xp.x, fb[ch - 1]);
            }
        }
        {
            const int   bb = 2 * p + 1 + PAR;
            const int   ch = T.chan[bb];
            const float wa = T.w[bb];
            if (wa != 0.f || ch != 0) {
                if (ch < NCH) fb[ch]     = fmaf(wa, xp.y, fb[ch]);
                if (ch >= 1)  fb[ch - 1] = fmaf(1.0f - wa, xp.y, fb[ch - 1]);
            }
        }
    }
}

// Role-split pipelined block: 1 block/CU (LDS 131584 B), 5 phases. In phase ph,
// waves 0-1 stage generation ph (128 frames, linear float4 -> fp16, 8-deep load
// pipeline) into slab[ph&1] while waves 2-3 run the full per-frame PLP pipeline on
// generation ph-1 from slab[(ph-1)&1]. One barrier per phase. Memory issue is
// continuous by PROGRAM ORDER (a staging wave is always active), not by luck.
// LDS layout: frame stride 257 halves (odd) -> read banks spiral, 2-way = free.
__global__ __launch_bounds__(TPB) void plp_kernel(const float* __restrict__ x,
                                                  float* __restrict__ out,
                                                  int nframes)
{
    using cfg::T;
    __shared__ __half slabH[2][CFRM * NBINS];    // 2 x 65792 B = 131584 B

    const int tid = threadIdx.x;
    const int w   = tid >> 6;                    // wave 0..3
    const long long B0    = (long long)blockIdx.x * (CFRM * GENS);
    const long long i4max = ((long long)nframes * NBINS) >> 2;   // total float4s

    #pragma unroll 1
    for (int ph = 0; ph <= GENS; ++ph) {
        if (ph < GENS && w < 2) {
            // ---- STAGE gen ph: waves 0,1 (threads 0..127) ----
            const int st = tid;                              // 0..127
            const long long Fg    = B0 + (long long)ph * CFRM;
            const long long base4 = (Fg * NBINS) >> 2;       // Fg % 4 == 0 -> exact
            const float4* src4 = reinterpret_cast<const float4*>(x);
            uint2* dst = reinterpret_cast<uint2*>(&slabH[ph & 1][0]);

            // 8224 float4 = 8 groups x (8 rounds x 128) + 32 tail; software-pipelined
            float4 cur[8];
            #pragma unroll
            for (int k = 0; k < 8; ++k) {
                long long gi = base4 + k * 128 + st;
                cur[k] = src4[gi < i4max ? gi : (i4max - 1)];
            }
            #pragma unroll
            for (int grp = 0; grp < 8; ++grp) {
                float4 nxt[8];
                if (grp < 7) {
                    #pragma unroll
                    for (int k = 0; k < 8; ++k) {
                        long long gi = base4 + (grp + 1) * 1024 + k * 128 + st;
                        nxt[k] = src4[gi < i4max ? gi : (i4max - 1)];
                    }
                }
                #pragma unroll
                for (int k = 0; k < 8; ++k) {
                    const int i = grp * 1024 + k * 128 + st; // local float4 idx
                    union { __half2 h[2]; uint2 u; } cv;
                    cv.h[0] = __float22half2_rn(make_float2(cur[k].x, cur[k].y));
                    cv.h[1] = __float22half2_rn(make_float2(cur[k].z, cur[k].w));
                    dst[i] = cv.u;                           // byte 8i, aligned b64
                }
                if (grp < 7) {
                    #pragma unroll
                    for (int k = 0; k < 8; ++k) cur[k] = nxt[k];
                }
            }
            if (st < 32) {                                   // tail 8224 - 8192
                long long gi = base4 + 8192 + st;
                const float4 v = src4[gi < i4max ? gi : (i4max - 1)];
                union { __half2 h[2]; uint2 u; } cv;
                cv.h[0] = __float22half2_rn(make_float2(v.x, v.y));
                cv.h[1] = __float22half2_rn(make_float2(v.z, v.w));
                dst[8192 + st] = cv.u;
            }
        }

        if (ph > 0 && w >= 2) {
            // ---- COMPUTE gen ph-1: waves 2,3 (128 frames, thread-per-frame) ----
            const int g   = ph - 1;
            const int par = w - 2;                           // frame parity
            const int l   = tid & 63;
            const int fl  = 2 * l + par;                     // local frame 0..127
            const long long frame = B0 + (long long)g * CFRM + fl;
            // half index fl*257+par is even for both parities -> aligned half2
            const __half2* fr2 = reinterpret_cast<const __half2*>(
                &slabH[g & 1][fl * NBINS + par]);

            float fb[NCH];
            #pragma unroll
            for (int c = 0; c < NCH; ++c) fb[c] = 0.f;

            if (par == 0) fbank_pairs<0>(fr2, fb);
            else          fbank_pairs<1>(fr2, fb);

            // ---- equal-loudness + cube-root compression (fast log/exp) ----
            float yv[NCH];
            #pragma unroll
            for (int c = 0; c < NCH; ++c) {
                float v = fmaxf(fb[c], 1e-5f) * T.eql[c];
                yv[c] = __expf(0.33f * __logf(v));
            }

            // ---- even/odd fold of y (42 taps incl. duplicated edges) ----
            float ye[21], yo[21];
            ye[0] = yv[0] + yv[39];  yo[0] = yv[0] - yv[39];
            #pragma unroll
            for (int jj = 1; jj <= 20; ++jj) {
                float aa = yv[jj - 1], bb = yv[40 - jj];
                ye[jj] = aa + bb;  yo[jj] = aa - bb;
            }

            // ---- folded cosine transform: 17 lags x 21 taps, literal coeffs ----
            float rr[NR];
            #pragma unroll
            for (int lg = 0; lg < NR; ++lg) {
                const float* yy = (lg & 1) ? yo : ye;
                float acc = 0.f;
                #pragma unroll
                for (int jj = 0; jj <= 20; ++jj) acc = fmaf(T.ctf[lg][jj], yy[jj], acc);
                rr[lg] = acc;
            }

            // ---- Levinson-Durbin (unrolled, v_rcp) ----
            float a[MORD];
            #pragma unroll
            for (int i = 0; i < MORD; ++i) a[i] = 0.f;
            float E = rr[0];
            #pragma unroll
            for (int i = 1; i <= MORD; ++i) {
                float acc = rr[i];
                #pragma unroll
                for (int jj = 0; jj < i - 1; ++jj) acc = fmaf(a[jj], rr[i - 1 - jj], acc);
                float k = -acc * __builtin_amdgcn_rcpf(E);
                const int half = (i - 1) / 2;
                #pragma unroll
                for (int jj = 0; jj < half; ++jj) {
                    float t1 = a[jj], t2 = a[i - 2 - jj];
                    a[jj]         = fmaf(k, t2, t1);
                    a[i - 2 - jj] = fmaf(k, t1, t2);
                }
                if ((i - 1) & 1) a[half] = fmaf(k, a[half], a[half]);
                a[i - 1] = k;
                E = E * (1.f - k * k);
            }

            // ---- cepstrum (ccs[k]=k*cc[k] keeps inner fma literal-free) ----
            float cc[NR], ccs[NR];
            #pragma unroll
            for (int m = 1; m <= MORD; ++m) {
                float acc = 0.f;
                #pragma unroll
                for (int k2 = 1; k2 < m; ++k2)
                    acc = fmaf(ccs[k2], a[m - k2 - 1], acc);
                float cm = -(a[m - 1] + acc * (1.0f / (float)m));
                cc[m]  = cm;
                ccs[m] = (float)m * cm;
            }

            // ---- direct stores: thread's 4x float4 cover its frame's 64B line ----
            if (frame < (long long)nframes) {
                float o[16];
                #pragma unroll
                for (int m = 1; m <= MORD; ++m) o[m - 1] = cc[m] * T.lift[m];

                float4* op = reinterpret_cast<float4*>(out + (size_t)frame * 16);
                op[0] = make_float4(o[0],  o[1],  o[2],  o[3]);
                op[1] = make_float4(o[4],  o[5],  o[6],  o[7]);
                op[2] = make_float4(o[8],  o[9],  o[10], o[11]);
                op[3] = make_float4(o[12], o[13], o[14], o[15]);
            }
        }

        __syncthreads();                         // phase boundary (uniform for all waves)
    }
}

extern "C" void kernel_launch(void* const* d_in, const int* in_sizes, int n_in,
                              void* d_out, int out_size, void* d_ws, size_t ws_size,
                              hipStream_t stream) {
    const float* x   = (const float*)d_in[0];
    float*      outp = (float*)d_out;
    int nframes = in_sizes[0] / NBINS;                       // 131072
    int nblocks = (nframes + CFRM * GENS - 1) / (CFRM * GENS);  // 256 = 1 block/CU
    plp_kernel<<<nblocks, TPB, 0, stream>>>(x, outp, nframes);
}

// Round 7
// 194.448 us; speedup vs baseline: 1.0365x; 1.0318x over previous
//
#include <hip/hip_runtime.h>
#include <hip/hip_fp16.h>

#define NCH   40
#define MORD  16
#define NR    17
#define NBINS 257
#define FPB   128                // frames per block (2 waves, each computes 64)
#define FSTR  258                // LDS frame stride in halves (129 dwords, odd -> free 2-way)

// ---------------- compile-time table generation (double precision) ----------------
namespace cfg {

constexpr double PI  = 3.14159265358979323846264338327950288;
constexpr double LN2 = 0.693147180559945309417232121458176568;

constexpr double cexp(double x) {
    double t = 1.0, s = 1.0;
    for (int i = 1; i < 40; ++i) { t *= x / i; s += t; }
    return s;
}

constexpr double clog(double z) {
    double lg = 0.0;
    while (z > 1.4142135623730951) { z *= 0.5; lg += LN2; }
    while (z < 0.7071067811865476) { z *= 2.0; lg -= LN2; }
    double u = (z - 1.0) / (z + 1.0), u2 = u * u, t = u, s = u;
    for (int k = 1; k < 24; ++k) { t *= u2; s += t / (2.0 * k + 1.0); }
    return lg + 2.0 * s;
}

constexpr double ccos(double x) {
    double tp = 2.0 * PI;
    double q = x / tp;
    long long k = (long long)(q + (q >= 0.0 ? 0.5 : -0.5));
    double r = x - (double)k * tp;
    double r2 = r * r, t = 1.0, s = 1.0;
    for (int i = 1; i < 20; ++i) { t *= -r2 / ((2.0 * i - 1.0) * (2.0 * i)); s += t; }
    return s;
}

constexpr double csin(double x) { return ccos(x - PI / 2.0); }

struct Tab {
    int   start[43];     // start[c] = first bin with t_b > c
    int   chan[257];     // segment id c(b), 0..40
    float w[257];        // t_b - c(b), in [0,1)
    float eql[NCH];
    float lift[NR];
    float ctf[NR][21];   // folded cosine: r[l] = sum_j ctf[l][j]*(ys[j] +- ys[41-j])
    constexpr Tab() : start(), chan(), w(), eql(), lift(), ctf() {
        const double lmax  = clog(87.0 / 7.0);
        const double U1127 = lmax / 41.0;
        for (int c = 0; c <= 41; ++c) {
            double thr = 22.4 * (cexp((double)c * U1127) - 1.0);
            int s = (int)thr + 1;
            if (s < 1) s = 1;
            if (s > 256) s = 256;
            start[c] = s;
        }
        start[42] = start[41];
        for (int c = 0; c <= 40; ++c) {
            for (int b = start[c]; b < start[c + 1]; ++b) {
                double mel = 1127.0 * clog(1.0 + (double)b * 31.25 / 700.0);
                double t   = mel / (1127.0 * U1127);
                w[b] = (float)(t - (double)c);
                chan[b] = c;
            }
        }
        for (int c = 0; c < NCH; ++c) {
            double cf = 700.0 * (cexp((double)(c + 1) * U1127) - 1.0);
            double f2 = cf * cf;
            double e  = f2 / (f2 + 160000.0);
            e = e * e * (f2 + 1440000.0) / (f2 + 9610000.0);
            eql[c] = (float)e;
        }
        for (int m = 0; m < NR; ++m)
            lift[m] = (float)(1.0 + 11.0 * csin(PI * (double)m / 22.0));
        lift[0] = 2.0f;
        for (int l = 0; l < NR; ++l)
            for (int j = 0; j <= 20; ++j) {
                double s = (j == 0) ? 1.0 : 2.0;
                ctf[l][j] = (float)(s * ccos(PI * (double)(j * l) / 41.0) / 82.0);
            }
    }
};

constexpr Tab T{};

} // namespace cfg

// ---- 128-thread block: coalesced fp32->fp16 staging of 2 slabs, then ALL
// ---- 128 threads (2 in-phase waves) run the register pipeline, 1 frame each.
__global__ __launch_bounds__(FPB) void plp_kernel(const float* __restrict__ x,
                                                  float* __restrict__ out,
                                                  int nframes)
{
    using cfg::T;
    __shared__ __half slab[FPB * FSTR];          // 66048 B -> 2 blocks/CU
    const int tid = threadIdx.x;
    const long long F0 = (long long)blockIdx.x * FPB;

    // ---- staging: 64 rounds, 2 frames per round; bins 1..256 -> LDS idx f*258+(b-1)
    {
        const int s  = tid >> 6;                 // 0/1: which frame of the pair
        const int ll = tid & 63;                 // lane within frame
        __half2* l2 = reinterpret_cast<__half2*>(slab);
        #pragma unroll 8
        for (int r = 0; r < 64; ++r) {
            const int fl = 2 * r + s;            // local frame 0..127
            long long fg = F0 + fl;
            if (fg > (long long)nframes - 1) fg = (long long)nframes - 1;
            const float* g = x + fg * NBINS + 1 + 4 * ll;   // bins 4ll+1..4ll+4
            float x0 = g[0], x1 = g[1], x2 = g[2], x3 = g[3];
            const int d = fl * 129 + 2 * ll;     // half2 index
            l2[d]     = __float22half2_rn(make_float2(x0, x1));
            l2[d + 1] = __float22half2_rn(make_float2(x2, x3));
        }
    }
    __syncthreads();

    const long long frame = F0 + tid;
    if (frame >= nframes) return;
    const __half2* fr2 = reinterpret_cast<const __half2*>(slab) + tid * 129;

    // ---- sparse mel filterbank: literal weights, compile-time channel targets ----
    float fb[NCH];
    #pragma unroll
    for (int c = 0; c < NCH; ++c) fb[c] = 0.f;

    #pragma unroll
    for (int p = 0; p < 128; ++p) {
        float2 xp = __half22float2(fr2[p]);      // bins 2p+1 (x), 2p+2 (y)
        {
            constexpr int b = 1;                 // placeholder to keep scope tidy
            (void)b;
        }
        {
            const int   bb = 2 * p + 1;
            const int   c  = T.chan[bb];
            const float wa = T.w[bb];
            if (c < 40) fb[c]     = fmaf(wa, xp.x, fb[c]);
            if (c >= 1) fb[c - 1] = fmaf(1.0f - wa, xp.x, fb[c - 1]);
        }
        if (2 * p + 2 <= 255) {
            const int   bb = 2 * p + 2;
            const int   c  = T.chan[bb];
            const float wa = T.w[bb];
            if (c < 40) fb[c]     = fmaf(wa, xp.y, fb[c]);
            if (c >= 1) fb[c - 1] = fmaf(1.0f - wa, xp.y, fb[c - 1]);
        }
    }

    // ---- equal-loudness + cube-root compression (fast log/exp), ys in regs ----
    float yv[NCH];
    #pragma unroll
    for (int c = 0; c < NCH; ++c) {
        float v = fmaxf(fb[c], 1e-5f) * T.eql[c];
        yv[c] = __expf(0.33f * __logf(v));
    }

    // ---- even/odd fold of y (42 taps incl. duplicated edges) ----
    float ye[21], yo[21];
    ye[0] = yv[0] + yv[39];  yo[0] = yv[0] - yv[39];       // ys[0], ys[41]
    #pragma unroll
    for (int j = 1; j <= 20; ++j) {
        float aa = yv[j - 1], bb = yv[40 - j];             // ys[j], ys[41-j]
        ye[j] = aa + bb;  yo[j] = aa - bb;
    }

    // ---- folded cosine transform: 17 lags x 21 taps, literal coefficients ----
    float r[NR];
    #pragma unroll
    for (int l = 0; l < NR; ++l) {
        const float* yy = (l & 1) ? yo : ye;
        float acc = 0.f;
        #pragma unroll
        for (int j = 0; j <= 20; ++j) acc = fmaf(T.ctf[l][j], yy[j], acc);
        r[l] = acc;
    }

    // ---- Levinson-Durbin (unrolled, v_rcp) ----
    float a[MORD];
    #pragma unroll
    for (int i = 0; i < MORD; ++i) a[i] = 0.f;
    float E = r[0];
    #pragma unroll
    for (int i = 1; i <= MORD; ++i) {
        float acc = r[i];
        #pragma unroll
        for (int j = 0; j < i - 1; ++j) acc = fmaf(a[j], r[i - 1 - j], acc);
        float k = -acc * __builtin_amdgcn_rcpf(E);
        const int half = (i - 1) / 2;
        #pragma unroll
        for (int j = 0; j < half; ++j) {
            float t1 = a[j], t2 = a[i - 2 - j];
            a[j]         = fmaf(k, t2, t1);
            a[i - 2 - j] = fmaf(k, t1, t2);
        }
        if ((i - 1) & 1) a[half] = fmaf(k, a[half], a[half]);
        a[i - 1] = k;
        E = E * (1.f - k * k);
    }

    // ---- cepstrum (c[0] unused; ccs[k]=k*cc[k] keeps inner fma literal-free) ----
    float cc[NR], ccs[NR];
    #pragma unroll
    for (int m = 1; m <= MORD; ++m) {
        float acc = 0.f;
        #pragma unroll
        for (int k2 = 1; k2 < m; ++k2)
            acc = fmaf(ccs[k2], a[m - k2 - 1], acc);
        float cm = -(a[m - 1] + acc * (1.0f / (float)m));
        cc[m]  = cm;
        ccs[m] = (float)m * cm;
    }

    float o[16];
    #pragma unroll
    for (int m = 1; m <= MORD; ++m) o[m - 1] = cc[m] * T.lift[m];

    float4* op = reinterpret_cast<float4*>(out + (size_t)frame * 16);
    op[0] = make_float4(o[0],  o[1],  o[2],  o[3]);
    op[1] = make_float4(o[4],  o[5],  o[6],  o[7]);
    op[2] = make_float4(o[8],  o[9],  o[10], o[11]);
    op[3] = make_float4(o[12], o[13], o[14], o[15]);
}

extern "C" void kernel_launch(void* const* d_in, const int* in_sizes, int n_in,
                              void* d_out, int out_size, void* d_ws, size_t ws_size,
                              hipStream_t stream) {
    const float* x   = (const float*)d_in[0];
    float*      outp = (float*)d_out;
    int nframes = in_sizes[0] / NBINS;                 // 131072
    int nblocks = (nframes + FPB - 1) / FPB;           // 1024
    plp_kernel<<<nblocks, FPB, 0, stream>>>(x, outp, nframes);
}